// Round 4
// baseline (143.316 us; speedup 1.0000x reference)
//
#include <hip/hip_runtime.h>
#include <hip/hip_bf16.h>

#define N 8192
#define D_IN 512
#define D_OUT 64
#define ALPHA 0.2f
#define SEG 176   // per-wave list capacity: Binom(2048,0.05) mean 102.4, sd 9.9 -> +7.4 sd
#define RPW 4     // rows per wave in the h kernel

// Kernel 1: h = input @ W, s1 = h@a1, s2 = h@a2.
// 4 rows per wave (lane = output dim): W column loaded once per k, reused x4;
// grid 512 blocks -> 2 waves/SIMD.
__global__ __launch_bounds__(256) void gat_h_kernel(
    const float* __restrict__ input, const float* __restrict__ W,
    const float* __restrict__ a, float* __restrict__ h,
    float* __restrict__ s1, float* __restrict__ s2)
{
    int wave = (blockIdx.x * 256 + threadIdx.x) >> 6;
    int lane = threadIdx.x & 63;
    int row0 = wave * RPW;
    const float* in0 = input + (size_t)row0 * D_IN;
    float a1 = a[lane], a2 = a[D_OUT + lane];
    float acc[RPW];
#pragma unroll
    for (int r = 0; r < RPW; ++r) acc[r] = 0.f;
#pragma unroll 4
    for (int k = 0; k < D_IN; ++k) {
        float wk = W[k * D_OUT + lane];
#pragma unroll
        for (int r = 0; r < RPW; ++r)
            acc[r] = fmaf(in0[(size_t)r * D_IN + k], wk, acc[r]);  // in0[..] wave-uniform
    }
#pragma unroll
    for (int r = 0; r < RPW; ++r) {
        h[((size_t)(row0 + r) << 6) + lane] = acc[r];
        float p1 = acc[r] * a1;
        float p2 = acc[r] * a2;
#pragma unroll
        for (int off = 32; off; off >>= 1) {
            p1 += __shfl_xor(p1, off, 64);
            p2 += __shfl_xor(p2, off, 64);
        }
        if (lane == 0) { s1[row0 + r] = p1; s2[row0 + r] = p2; }
    }
}

// Kernel 2: ONE BLOCK PER ROW, 4 waves cooperate.
//  Scan: wave ws covers cols [ws*2048,(ws+1)*2048) = 8 float4-tiles (reg dbuf),
//        ballot+mbcnt-compacts {j, w=exp(leaky(e)-eref)} into its LDS segment.
//  Gather: each wave walks its own segment, 8 L2 h-loads in flight, LDS prefetch.
//  Combine: LDS reduce of 4 partial acc[64] + 4 lsum; wave 0 applies elu, writes.
// Softmax ref = diagonal logit (adj[i][i]=1 always) -> denom >= 1, fp32 exact.
__global__ __launch_bounds__(256) void gat_attn_kernel(
    const float* __restrict__ adj, const float* __restrict__ h,
    const float* __restrict__ s1, const float* __restrict__ s2,
    float* __restrict__ out)
{
    __shared__ uint2 seg[4][SEG];     // 5.6 KB
    __shared__ float racc[4][64];     // 1 KB
    __shared__ float rls[4];

    int row  = blockIdx.x;
    int lane = threadIdx.x & 63;
    int ws   = threadIdx.x >> 6;

    const float4* adj_row = (const float4*)(adj + (size_t)row * N);
    const float4* s2v     = (const float4*)s2;
    float s1i  = s1[row];
    float eref = s1i + s2[row];
    eref = eref > 0.f ? eref : ALPHA * eref;   // leaky_relu(diag logit)

    // ---- Scan + compact (8 tiles per wave, double-buffered) ----
    float lsum = 0.f;
    int cnt = 0;
    int cbase = ws << 11;                       // ws * 2048
    float4 av = adj_row[(cbase >> 2) + lane];
    float4 sv = s2v[(cbase >> 2) + lane];
    for (int t = 0; t < 8; ++t) {
        int j0 = cbase + (t << 8);
        float4 avn, svn;
        if (t < 7) {
            int o = ((j0 + 256) >> 2) + lane;
            avn = adj_row[o];
            svn = s2v[o];
        }
#pragma unroll
        for (int z = 0; z < 4; ++z) {
            bool nb = (&av.x)[z] > 0.f;
            float e = s1i + (&sv.x)[z];
            e = e > 0.f ? e : ALPHA * e;        // leaky_relu
            float w = nb ? __expf(e - eref) : 0.f;
            lsum += w;
            unsigned long long m = __ballot(nb);
            if (nb) {
                int prefix = __builtin_amdgcn_mbcnt_hi(
                    (unsigned)(m >> 32),
                    __builtin_amdgcn_mbcnt_lo((unsigned)m, 0u));
                int idx = cnt + prefix;
                if (idx < SEG)                  // safety clamp (P(overflow)~1e-9)
                    seg[ws][idx] =
                        make_uint2((unsigned)(j0 + (lane << 2) + z), __float_as_uint(w));
            }
            cnt += __popcll(m);
        }
        if (t < 7) { av = avn; sv = svn; }
    }
    if (cnt > SEG) cnt = SEG;
#pragma unroll
    for (int off = 32; off; off >>= 1) lsum += __shfl_xor(lsum, off, 64);

    // ---- Gather own segment: 8 loads in flight + LDS prefetch ----
    float acc0 = 0.f, acc1 = 0.f, acc2 = 0.f, acc3 = 0.f;
    int nb8 = cnt & ~7;
    uint2 cur[8];
    if (nb8) {
#pragma unroll
        for (int t = 0; t < 8; ++t) cur[t] = seg[ws][t];
    }
    for (int k = 0; k < nb8; k += 8) {
        float wv[8], hv[8];
#pragma unroll
        for (int t = 0; t < 8; ++t) {
            int j = __builtin_amdgcn_readfirstlane((int)cur[t].x);  // scalar base
            wv[t] = __uint_as_float(cur[t].y);
            hv[t] = h[((size_t)j << 6) + lane];   // s-base + lane offset, coalesced
        }
        if (k + 8 < nb8) {
#pragma unroll
            for (int t = 0; t < 8; ++t) cur[t] = seg[ws][k + 8 + t];
        }
#pragma unroll
        for (int t = 0; t < 8; ++t) {
            float v = fmaf(wv[t], hv[t], (t & 3) == 0 ? acc0 : (t & 3) == 1 ? acc1
                                        : (t & 3) == 2 ? acc2 : acc3);
            if ((t & 3) == 0) acc0 = v; else if ((t & 3) == 1) acc1 = v;
            else if ((t & 3) == 2) acc2 = v; else acc3 = v;
        }
    }
    for (int k = nb8; k < cnt; ++k) {
        uint2 e = seg[ws][k];
        int j = __builtin_amdgcn_readfirstlane((int)e.x);
        acc0 = fmaf(__uint_as_float(e.y), h[((size_t)j << 6) + lane], acc0);
    }

    // ---- Combine across the 4 waves ----
    racc[ws][lane] = (acc0 + acc1) + (acc2 + acc3);
    if (lane == 0) rls[ws] = lsum;
    __syncthreads();
    if (ws == 0) {
        float acc = (racc[0][lane] + racc[1][lane]) + (racc[2][lane] + racc[3][lane]);
        float l = (rls[0] + rls[1]) + (rls[2] + rls[3]);
        float o = acc / l;
        out[((size_t)row << 6) + lane] = o > 0.f ? o : expm1f(o);   // elu
    }
}

extern "C" void kernel_launch(void* const* d_in, const int* in_sizes, int n_in,
                              void* d_out, int out_size, void* d_ws, size_t ws_size,
                              hipStream_t stream) {
    const float* input = (const float*)d_in[0];   // (8192, 512) f32
    const float* adj   = (const float*)d_in[1];   // (8192, 8192) f32
    const float* W     = (const float*)d_in[2];   // (512, 64) f32
    const float* a     = (const float*)d_in[3];   // (128, 1) f32
    float* out = (float*)d_out;                   // (8192, 64) f32

    float* h  = (float*)d_ws;                     // N*D_OUT floats = 2 MB
    float* s1 = h + (size_t)N * D_OUT;
    float* s2 = s1 + N;

    gat_h_kernel<<<N / (RPW * 4), 256, 0, stream>>>(input, W, a, h, s1, s2);
    gat_attn_kernel<<<N, 256, 0, stream>>>(adj, h, s1, s2, out);
}

// Round 5
// 123.516 us; speedup vs baseline: 1.1603x; 1.1603x over previous
//
#include <hip/hip_runtime.h>
#include <hip/hip_bf16.h>

#define N 8192
#define D_IN 512
#define D_OUT 64
#define ALPHA 0.2f
#define BM 16
#define BK 128
#define NSTEP (N / BK)   // 64

typedef __attribute__((ext_vector_type(4))) float f32x4;
typedef __attribute__((ext_vector_type(8))) short bf16x8;

static __device__ __forceinline__ unsigned pk_bf16(float lo, float hi) {
    unsigned ulo = __bfloat16_as_ushort(__float2bfloat16(lo));
    unsigned uhi = __bfloat16_as_ushort(__float2bfloat16(hi));
    return (uhi << 16) | ulo;
}

#define BARRIER() do { \
    asm volatile("s_waitcnt lgkmcnt(0)" ::: "memory"); \
    __builtin_amdgcn_sched_barrier(0); \
    __builtin_amdgcn_s_barrier(); \
    __builtin_amdgcn_sched_barrier(0); \
} while (0)

// Kernel 1: h = input @ W -> hbT (bf16, transposed [64][8192]); s1 = h@a1, s2 = h@a2 (fp32).
// 8 rows per wave, lane = output dim d: lane already holds the 8 j-values of its
// hbT row segment -> direct uint4 store, no transpose needed.
__global__ __launch_bounds__(256) void gat_h_kernel(
    const float* __restrict__ input, const float* __restrict__ W,
    const float* __restrict__ a, unsigned short* __restrict__ hbT,
    float* __restrict__ s1, float* __restrict__ s2)
{
    int wave = (blockIdx.x * 256 + threadIdx.x) >> 6;
    int lane = threadIdx.x & 63;
    int row0 = wave * 8;
    const float* in0 = input + (size_t)row0 * D_IN;
    float a1 = a[lane], a2 = a[D_OUT + lane];
    float acc[8];
#pragma unroll
    for (int r = 0; r < 8; ++r) acc[r] = 0.f;
#pragma unroll 4
    for (int k = 0; k < D_IN; ++k) {
        float wk = W[k * D_OUT + lane];
#pragma unroll
        for (int r = 0; r < 8; ++r)
            acc[r] = fmaf(in0[(size_t)r * D_IN + k], wk, acc[r]);  // uniform-addr broadcast
    }
    uint4 hv;
    hv.x = pk_bf16(acc[0], acc[1]);
    hv.y = pk_bf16(acc[2], acc[3]);
    hv.z = pk_bf16(acc[4], acc[5]);
    hv.w = pk_bf16(acc[6], acc[7]);
    *(uint4*)(hbT + (size_t)lane * N + row0) = hv;
#pragma unroll
    for (int r = 0; r < 8; ++r) {
        float p1 = acc[r] * a1;
        float p2 = acc[r] * a2;
#pragma unroll
        for (int off = 32; off; off >>= 1) {
            p1 += __shfl_xor(p1, off, 64);
            p2 += __shfl_xor(p2, off, 64);
        }
        if (lane == 0) { s1[row0 + r] = p1; s2[row0 + r] = p2; }
    }
}

struct Pref { float4 a0, a1; uint4 h0, h1, h2, h3; };

static __device__ __forceinline__ void issue(Pref& p, const float* ab,
                                             const unsigned short* hb, int j0) {
    p.a0 = *(const float4*)(ab + j0);
    p.a1 = *(const float4*)(ab + j0 + 4);
    p.h0 = *(const uint4*)(hb + j0);
    p.h1 = *(const uint4*)(hb + j0 + 8);
    p.h2 = *(const uint4*)(hb + j0 + 16);
    p.h3 = *(const uint4*)(hb + j0 + 24);
}

// Kernel 2: dense masked-softmax @ h via MFMA, flash-style.
// Block = 16 rows x 64 out-cols, 4 waves (each wave one 16x16 C-frag along n).
// Per K-step (BK=128 cols): adj tile in regs (2-step prefetch) -> w=exp(leaky-e)
// masked -> bf16 P tile (XOR-swizzled LDS) + staged hbT tile; 4 MFMA/wave.
// One raw barrier + lgkmcnt(0) per step; vmcnt stays counted (prefetch lives).
__global__ __launch_bounds__(256, 2) void gat_flash_kernel(
    const float* __restrict__ adj, const unsigned short* __restrict__ hbT,
    const float* __restrict__ s1, const float* __restrict__ s2,
    float* __restrict__ out)
{
    __shared__ float s2l[N];                              // 32 KB
    __shared__ __align__(16) unsigned char Pl[2][BM * BK * 2];      // 2 x 4 KB
    __shared__ __align__(16) unsigned char Hl[2][D_OUT * BK * 2];   // 2 x 16 KB
    __shared__ float lsl[BM];

    const int tid  = threadIdx.x;
    const int lane = tid & 63;
    const int wv   = tid >> 6;
    const int r    = tid >> 4;          // adj row 0..15 (fixed per thread)
    const int s    = tid & 15;          // 8-col chunk within row
    const int hd   = tid >> 2;          // hbT d-row 0..63
    const int hc   = tid & 3;           // hbT 32-col chunk
    const int rg   = blockIdx.x * BM + r;

    // stage s2 into LDS (whole vector, read per K-step by all threads)
    {
        const float4* src = (const float4*)s2;
        float4* dst = (float4*)s2l;
        for (int i = tid; i < N / 4; i += 256) dst[i] = src[i];
    }
    const float* adj_base = adj + (size_t)rg * N + s * 8;
    const unsigned short* hb_base = hbT + (size_t)hd * N + hc * 32;
    float s1r = s1[rg];
    float eref;                          // set after s2l ready
    float lsum = 0.f;
    f32x4 acc = {0.f, 0.f, 0.f, 0.f};

    auto stage = [&](const Pref& p, int j0, int b) {
        float4 s2a = *(const float4*)(s2l + j0 + s * 8);
        float4 s2b = *(const float4*)(s2l + j0 + s * 8 + 4);
        const float* av0 = (const float*)&p.a0;
        const float* av1 = (const float*)&p.a1;
        const float* sv0 = (const float*)&s2a;
        const float* sv1 = (const float*)&s2b;
        float w[8];
#pragma unroll
        for (int z = 0; z < 4; ++z) {
            float e0 = s1r + sv0[z]; e0 = e0 > 0.f ? e0 : ALPHA * e0;   // leaky_relu
            float e1 = s1r + sv1[z]; e1 = e1 > 0.f ? e1 : ALPHA * e1;
            float w0 = __expf(e0 - eref);
            float w1 = __expf(e1 - eref);
            w[z]     = av0[z] > 0.f ? w0 : 0.f;
            w[z + 4] = av1[z] > 0.f ? w1 : 0.f;
        }
#pragma unroll
        for (int z = 0; z < 8; ++z) lsum += w[z];
        uint4 pk;
        pk.x = pk_bf16(w[0], w[1]); pk.y = pk_bf16(w[2], w[3]);
        pk.z = pk_bf16(w[4], w[5]); pk.w = pk_bf16(w[6], w[7]);
        *(uint4*)(&Pl[b][r * 256 + ((s * 16) ^ ((r & 7) << 4))]) = pk;
        *(uint4*)(&Hl[b][hd * 256 + ((hc * 64 +  0) ^ ((hd & 7) << 4))]) = p.h0;
        *(uint4*)(&Hl[b][hd * 256 + ((hc * 64 + 16) ^ ((hd & 7) << 4))]) = p.h1;
        *(uint4*)(&Hl[b][hd * 256 + ((hc * 64 + 32) ^ ((hd & 7) << 4))]) = p.h2;
        *(uint4*)(&Hl[b][hd * 256 + ((hc * 64 + 48) ^ ((hd & 7) << 4))]) = p.h3;
    };

    auto mfma_step = [&](int c) {
        const unsigned char* Pc = Pl[c];
        const unsigned char* Hc = Hl[c];
        const int i  = lane & 15;
        const int kb = lane >> 4;
        const int dd = wv * 16 + (lane & 15);
#pragma unroll
        for (int kk = 0; kk < 4; ++kk) {
            uint4 ua = *(const uint4*)(Pc + i * 256 + ((kk * 64 + kb * 16) ^ ((i & 7) << 4)));
            uint4 ub = *(const uint4*)(Hc + dd * 256 + ((kk * 64 + kb * 16) ^ ((dd & 7) << 4)));
            acc = __builtin_amdgcn_mfma_f32_16x16x32_bf16(
                __builtin_bit_cast(bf16x8, ua), __builtin_bit_cast(bf16x8, ub), acc, 0, 0, 0);
        }
    };

    Pref RA, RB;
    issue(RA, adj_base, hb_base, 0);
    issue(RB, adj_base, hb_base, BK);
    __syncthreads();                       // s2l ready (one-time full drain, ok)
    {
        float ed = s1r + s2l[rg];          // diagonal logit (adj[i][i]=1 always)
        eref = ed > 0.f ? ed : ALPHA * ed;
    }
    stage(RA, 0, 0);
    issue(RA, adj_base, hb_base, 2 * BK);
    BARRIER();

    for (int ks = 0; ks < NSTEP; ks += 2) {
        // even: compute buf0 (step ks), stage ks+1 -> buf1, issue ks+3 -> RB
        mfma_step(0);
        stage(RB, (ks + 1) * BK, 1);
        if (ks + 3 < NSTEP) issue(RB, adj_base, hb_base, (ks + 3) * BK);
        BARRIER();
        // odd: compute buf1 (step ks+1), stage ks+2 -> buf0, issue ks+4 -> RA
        mfma_step(1);
        if (ks + 2 < NSTEP) {
            stage(RA, (ks + 2) * BK, 0);
            if (ks + 4 < NSTEP) issue(RA, adj_base, hb_base, (ks + 4) * BK);
        }
        BARRIER();
    }

    // lsum: reduce over the 16 threads sharing row r (16-lane groups in-wave)
#pragma unroll
    for (int off = 8; off; off >>= 1) lsum += __shfl_xor(lsum, off, 64);
    if ((tid & 15) == 0) lsl[r] = lsum;
    __syncthreads();

    // epilogue: C/D frag -> row i=(lane>>4)*4+reg, col=lane&15 (+wave n-offset)
    const int dd = wv * 16 + (lane & 15);
#pragma unroll
    for (int reg = 0; reg < 4; ++reg) {
        int i = (lane >> 4) * 4 + reg;
        float o = acc[reg] / lsl[i];
        o = o > 0.f ? o : expm1f(o);       // elu
        out[(size_t)(blockIdx.x * BM + i) * 64 + dd] = o;
    }
}

extern "C" void kernel_launch(void* const* d_in, const int* in_sizes, int n_in,
                              void* d_out, int out_size, void* d_ws, size_t ws_size,
                              hipStream_t stream) {
    const float* input = (const float*)d_in[0];   // (8192, 512) f32
    const float* adj   = (const float*)d_in[1];   // (8192, 8192) f32
    const float* W     = (const float*)d_in[2];   // (512, 64) f32
    const float* a     = (const float*)d_in[3];   // (128, 1) f32
    float* out = (float*)d_out;                   // (8192, 64) f32

    unsigned short* hbT = (unsigned short*)d_ws;  // [64][8192] bf16 = 1 MB
    float* s1 = (float*)(hbT + (size_t)N * D_OUT);
    float* s2 = s1 + N;

    gat_h_kernel<<<256, 256, 0, stream>>>(input, W, a, hbT, s1, s2);
    gat_flash_kernel<<<N / BM, 256, 0, stream>>>(adj, hbT, s1, s2, out);
}

// Round 6
// 119.950 us; speedup vs baseline: 1.1948x; 1.0297x over previous
//
#include <hip/hip_runtime.h>
#include <hip/hip_bf16.h>

#define N 8192
#define D_IN 512
#define D_OUT 64
#define ALPHA 0.2f
#define BM 16
#define BK 128
#define NSTEP (N / BK)   // 64

typedef __attribute__((ext_vector_type(4))) float f32x4;
typedef __attribute__((ext_vector_type(8))) short bf16x8;

static __device__ __forceinline__ unsigned pk_bf16(float lo, float hi) {
    unsigned ulo = __bfloat16_as_ushort(__float2bfloat16(lo));
    unsigned uhi = __bfloat16_as_ushort(__float2bfloat16(hi));
    return (uhi << 16) | ulo;
}

#define BARRIER() do { \
    asm volatile("s_waitcnt lgkmcnt(0)" ::: "memory"); \
    __builtin_amdgcn_sched_barrier(0); \
    __builtin_amdgcn_s_barrier(); \
    __builtin_amdgcn_sched_barrier(0); \
} while (0)

// Kernel 1: h = input @ W -> hbT (bf16, transposed [64][8192]); s1 = h@a1, s2 = h@a2.
// 4 rows per wave (grid 512 -> 2 waves/SIMD), lane = output dim d.
__global__ __launch_bounds__(256) void gat_h_kernel(
    const float* __restrict__ input, const float* __restrict__ W,
    const float* __restrict__ a, unsigned short* __restrict__ hbT,
    float* __restrict__ s1, float* __restrict__ s2)
{
    int wave = (blockIdx.x * 256 + threadIdx.x) >> 6;
    int lane = threadIdx.x & 63;
    int row0 = wave * 4;
    const float* in0 = input + (size_t)row0 * D_IN;
    float a1 = a[lane], a2 = a[D_OUT + lane];
    float acc[4];
#pragma unroll
    for (int r = 0; r < 4; ++r) acc[r] = 0.f;
#pragma unroll 4
    for (int k = 0; k < D_IN; ++k) {
        float wk = W[k * D_OUT + lane];
#pragma unroll
        for (int r = 0; r < 4; ++r)
            acc[r] = fmaf(in0[(size_t)r * D_IN + k], wk, acc[r]);  // uniform-addr broadcast
    }
    uint2 hv;
    hv.x = pk_bf16(acc[0], acc[1]);
    hv.y = pk_bf16(acc[2], acc[3]);
    *(uint2*)(hbT + (size_t)lane * N + row0) = hv;
#pragma unroll
    for (int r = 0; r < 4; ++r) {
        float p1 = acc[r] * a1;
        float p2 = acc[r] * a2;
#pragma unroll
        for (int off = 32; off; off >>= 1) {
            p1 += __shfl_xor(p1, off, 64);
            p2 += __shfl_xor(p2, off, 64);
        }
        if (lane == 0) { s1[row0 + r] = p1; s2[row0 + r] = p2; }
    }
}

struct Pref { float4 a0, a1, s0, s1; uint4 h0, h1, h2, h3; };

static __device__ __forceinline__ void issue(Pref& p, const float* ab,
                                             const float* sb,
                                             const unsigned short* hb, int j0) {
    p.a0 = *(const float4*)(ab + j0);
    p.a1 = *(const float4*)(ab + j0 + 4);
    p.s0 = *(const float4*)(sb + j0);       // 16-way redundant in block -> L1
    p.s1 = *(const float4*)(sb + j0 + 4);
    p.h0 = *(const uint4*)(hb + j0);
    p.h1 = *(const uint4*)(hb + j0 + 8);
    p.h2 = *(const uint4*)(hb + j0 + 16);
    p.h3 = *(const uint4*)(hb + j0 + 24);
}

// Kernel 2: dense masked-softmax @ h via MFMA, flash-style.
// Block = 16 rows x 64 out-cols, 4 waves (one 16x16 C-frag each along n).
// Per K-step (BK=128): adj+s2+hbT in regs (2-step prefetch) -> w=exp(leaky-e)
// masked -> bf16 P tile (swizzled LDS) + staged hbT tile; 4 MFMA/wave.
// One raw barrier + lgkmcnt(0) per step; vmcnt stays counted.
// LDS 40.1 KB -> 3 blocks/CU (12 waves/CU) for latency hiding.
__global__ __launch_bounds__(256, 3) void gat_flash_kernel(
    const float* __restrict__ adj, const unsigned short* __restrict__ hbT,
    const float* __restrict__ s1, const float* __restrict__ s2,
    float* __restrict__ out)
{
    __shared__ __align__(16) unsigned char Pl[2][BM * BK * 2];      // 2 x 4 KB
    __shared__ __align__(16) unsigned char Hl[2][D_OUT * BK * 2];   // 2 x 16 KB
    __shared__ float lsl[BM];

    const int tid  = threadIdx.x;
    const int lane = tid & 63;
    const int wv   = tid >> 6;
    const int r    = tid >> 4;          // adj row 0..15 (fixed per thread)
    const int s    = tid & 15;          // 8-col chunk within row
    const int hd   = tid >> 2;          // hbT d-row 0..63
    const int hc   = tid & 3;           // hbT 32-col chunk
    const int rg   = blockIdx.x * BM + r;

    const float* adj_base = adj + (size_t)rg * N + s * 8;
    const float* s2_base  = s2 + s * 8;
    const unsigned short* hb_base = hbT + (size_t)hd * N + hc * 32;
    float s1r = s1[rg];
    float eref = s1r + s2[rg];                    // diagonal logit (adj[i][i]=1)
    eref = eref > 0.f ? eref : ALPHA * eref;      // leaky_relu
    float lsum = 0.f;
    f32x4 acc = {0.f, 0.f, 0.f, 0.f};

    auto stage = [&](const Pref& p, int b) {
        const float* av0 = (const float*)&p.a0;
        const float* av1 = (const float*)&p.a1;
        const float* sv0 = (const float*)&p.s0;
        const float* sv1 = (const float*)&p.s1;
        float w[8];
#pragma unroll
        for (int z = 0; z < 4; ++z) {
            float e0 = s1r + sv0[z]; e0 = e0 > 0.f ? e0 : ALPHA * e0;   // leaky_relu
            float e1 = s1r + sv1[z]; e1 = e1 > 0.f ? e1 : ALPHA * e1;
            float w0 = __expf(e0 - eref);
            float w1 = __expf(e1 - eref);
            w[z]     = av0[z] > 0.f ? w0 : 0.f;
            w[z + 4] = av1[z] > 0.f ? w1 : 0.f;
        }
#pragma unroll
        for (int z = 0; z < 8; ++z) lsum += w[z];
        uint4 pk;
        pk.x = pk_bf16(w[0], w[1]); pk.y = pk_bf16(w[2], w[3]);
        pk.z = pk_bf16(w[4], w[5]); pk.w = pk_bf16(w[6], w[7]);
        *(uint4*)(&Pl[b][r * 256 + ((s * 16) ^ ((r & 7) << 4))]) = pk;
        *(uint4*)(&Hl[b][hd * 256 + ((hc * 64 +  0) ^ ((hd & 7) << 4))]) = p.h0;
        *(uint4*)(&Hl[b][hd * 256 + ((hc * 64 + 16) ^ ((hd & 7) << 4))]) = p.h1;
        *(uint4*)(&Hl[b][hd * 256 + ((hc * 64 + 32) ^ ((hd & 7) << 4))]) = p.h2;
        *(uint4*)(&Hl[b][hd * 256 + ((hc * 64 + 48) ^ ((hd & 7) << 4))]) = p.h3;
    };

    auto mfma_step = [&](int c) {
        const unsigned char* Pc = Pl[c];
        const unsigned char* Hc = Hl[c];
        const int i  = lane & 15;
        const int kb = lane >> 4;
        const int dd = wv * 16 + (lane & 15);
#pragma unroll
        for (int kk = 0; kk < 4; ++kk) {
            uint4 ua = *(const uint4*)(Pc + i * 256 + ((kk * 64 + kb * 16) ^ ((i & 7) << 4)));
            uint4 ub = *(const uint4*)(Hc + dd * 256 + ((kk * 64 + kb * 16) ^ ((dd & 7) << 4)));
            acc = __builtin_amdgcn_mfma_f32_16x16x32_bf16(
                __builtin_bit_cast(bf16x8, ua), __builtin_bit_cast(bf16x8, ub), acc, 0, 0, 0);
        }
    };

    Pref RA, RB;
    issue(RA, adj_base, s2_base, hb_base, 0);
    issue(RB, adj_base, s2_base, hb_base, BK);
    stage(RA, 0);
    issue(RA, adj_base, s2_base, hb_base, 2 * BK);
    BARRIER();

    for (int ks = 0; ks < NSTEP; ks += 2) {
        // even: compute buf0 (step ks), stage ks+1 -> buf1, issue ks+3 -> RB
        mfma_step(0);
        stage(RB, 1);
        if (ks + 3 < NSTEP) issue(RB, adj_base, s2_base, hb_base, (ks + 3) * BK);
        BARRIER();
        // odd: compute buf1 (step ks+1), stage ks+2 -> buf0, issue ks+4 -> RA
        mfma_step(1);
        if (ks + 2 < NSTEP) {
            stage(RA, 0);
            if (ks + 4 < NSTEP) issue(RA, adj_base, s2_base, hb_base, (ks + 4) * BK);
        }
        BARRIER();
    }

    // lsum: reduce over the 16 threads sharing row r
#pragma unroll
    for (int off = 8; off; off >>= 1) lsum += __shfl_xor(lsum, off, 64);
    if ((tid & 15) == 0) lsl[r] = lsum;
    __syncthreads();

    // epilogue: C/D frag -> row i=(lane>>4)*4+reg, col=lane&15 (+wave n-offset)
    const int dd = wv * 16 + (lane & 15);
#pragma unroll
    for (int reg = 0; reg < 4; ++reg) {
        int i = (lane >> 4) * 4 + reg;
        float o = acc[reg] / lsl[i];
        o = o > 0.f ? o : expm1f(o);       // elu
        out[(size_t)(blockIdx.x * BM + i) * 64 + dd] = o;
    }
}

extern "C" void kernel_launch(void* const* d_in, const int* in_sizes, int n_in,
                              void* d_out, int out_size, void* d_ws, size_t ws_size,
                              hipStream_t stream) {
    const float* input = (const float*)d_in[0];   // (8192, 512) f32
    const float* adj   = (const float*)d_in[1];   // (8192, 8192) f32
    const float* W     = (const float*)d_in[2];   // (512, 64) f32
    const float* a     = (const float*)d_in[3];   // (128, 1) f32
    float* out = (float*)d_out;                   // (8192, 64) f32

    unsigned short* hbT = (unsigned short*)d_ws;  // [64][8192] bf16 = 1 MB
    float* s1 = (float*)(hbT + (size_t)N * D_OUT);
    float* s2 = s1 + N;

    gat_h_kernel<<<512, 256, 0, stream>>>(input, W, a, hbT, s1, s2);
    gat_flash_kernel<<<N / BM, 256, 0, stream>>>(adj, hbT, s1, s2, out);
}

// Round 7
// 114.859 us; speedup vs baseline: 1.2478x; 1.0443x over previous
//
#include <hip/hip_runtime.h>
#include <hip/hip_bf16.h>

#define N 8192
#define D_IN 512
#define D_OUT 64
#define ALPHA 0.2f
#define BM 16
#define BK 128
#define NSH 32            // steps per half (split-K x2): 4096/128

typedef __attribute__((ext_vector_type(4))) float f32x4;
typedef __attribute__((ext_vector_type(8))) short bf16x8;

static __device__ __forceinline__ unsigned pk_bf16(float lo, float hi) {
    unsigned ulo = __bfloat16_as_ushort(__float2bfloat16(lo));
    unsigned uhi = __bfloat16_as_ushort(__float2bfloat16(hi));
    return (uhi << 16) | ulo;
}

#define BARRIER() do { \
    asm volatile("s_waitcnt lgkmcnt(0)" ::: "memory"); \
    __builtin_amdgcn_sched_barrier(0); \
    __builtin_amdgcn_s_barrier(); \
    __builtin_amdgcn_sched_barrier(0); \
} while (0)

// Kernel 1: h = input @ W; emit h^T directly as pre-swizzled MFMA B-fragments.
// hpk element (j,d) lives at frag(ks=j>>7, wv=d>>4, kk=(j>>5)&3)[lane=(kb<<4)|dd][e=j&7],
// frag = 64 lanes x 8 bf16 = 1024 B. Also s1 = h@a1, s2 = h@a2 (fp32).
__global__ __launch_bounds__(256) void gat_h_kernel(
    const float* __restrict__ input, const float* __restrict__ W,
    const float* __restrict__ a, unsigned short* __restrict__ hpk,
    float* __restrict__ s1, float* __restrict__ s2)
{
    int wave = (blockIdx.x * 256 + threadIdx.x) >> 6;
    int lane = threadIdx.x & 63;
    int row0 = wave * 4;                      // row0 & 7 in {0,4}
    const float* in0 = input + (size_t)row0 * D_IN;
    float a1 = a[lane], a2 = a[D_OUT + lane];
    float acc[4];
#pragma unroll
    for (int r = 0; r < 4; ++r) acc[r] = 0.f;
#pragma unroll 4
    for (int k = 0; k < D_IN; ++k) {
        float wk = W[k * D_OUT + lane];
#pragma unroll
        for (int r = 0; r < 4; ++r)
            acc[r] = fmaf(in0[(size_t)r * D_IN + k], wk, acc[r]);  // uniform-addr broadcast
    }
    // scatter into fragment layout (4 consecutive e-slots -> one uint2 store)
    {
        int ks = row0 >> 7, kk = (row0 >> 5) & 3, kb = (row0 >> 3) & 3, eo = row0 & 7;
        int wvd = lane >> 4, dd = lane & 15;
        size_t off = ((size_t)(((ks * 4 + wvd) * 4 + kk) * 64) + kb * 16 + dd) * 8 + eo;
        uint2 hv;
        hv.x = pk_bf16(acc[0], acc[1]);
        hv.y = pk_bf16(acc[2], acc[3]);
        *(uint2*)(hpk + off) = hv;
    }
#pragma unroll
    for (int r = 0; r < 4; ++r) {
        float p1 = acc[r] * a1;
        float p2 = acc[r] * a2;
#pragma unroll
        for (int off = 32; off; off >>= 1) {
            p1 += __shfl_xor(p1, off, 64);
            p2 += __shfl_xor(p2, off, 64);
        }
        if (lane == 0) { s1[row0 + r] = p1; s2[row0 + r] = p2; }
    }
}

struct ASP { float4 a0, a1, s0, s1; };   // adj + s2 for one step (consumed by stage)
struct UBP { uint4 b0, b1, b2, b3; };    // 4 B-fragments for one step (consumed by mfma)

static __device__ __forceinline__ void issue_as(ASP& p, const float* ab,
                                                const float* sb, int j0) {
    p.a0 = *(const float4*)(ab + j0);
    p.a1 = *(const float4*)(ab + j0 + 4);
    p.s0 = *(const float4*)(sb + j0);       // 16-way redundant in block -> L1
    p.s1 = *(const float4*)(sb + j0 + 4);
}
static __device__ __forceinline__ void issue_ub(UBP& p, const unsigned short* hb,
                                                int ksg) {
    const unsigned short* f = hb + ((size_t)ksg << 13);   // ksg*8192 elements
    p.b0 = *(const uint4*)(f);
    p.b1 = *(const uint4*)(f + 512);
    p.b2 = *(const uint4*)(f + 1024);
    p.b3 = *(const uint4*)(f + 1536);
}

// Kernel 2: dense masked-softmax @ h via MFMA, flash-style, split-K x2.
// Block = 16 rows x 64 out-cols x half the j-range (32 steps of BK=128).
// Per step: adj+s2 in regs (2-step prefetch) -> w=exp(leaky(e)-eref) masked ->
// bf16 P tile (swizzled LDS, the only LDS use); B-operands come straight from
// the pre-swizzled hpk fragments in L2 (1 coalesced dwordx4 per MFMA).
// Writes un-normalized pacc + plsum partials; reduce kernel divides + elu.
__global__ __launch_bounds__(256, 4) void gat_flash_kernel(
    const float* __restrict__ adj, const unsigned short* __restrict__ hpk,
    const float* __restrict__ s1, const float* __restrict__ s2,
    float* __restrict__ pacc, float* __restrict__ plsum)
{
    __shared__ __align__(16) unsigned char Pl[2][BM * BK * 2];      // 2 x 4 KB

    const int tid  = threadIdx.x;
    const int lane = tid & 63;
    const int wv   = tid >> 6;
    const int r    = tid >> 4;          // adj row 0..15 (fixed per thread)
    const int s    = tid & 15;          // 8-col chunk within row
    const int hf   = blockIdx.x >> 9;   // K-half
    const int rb   = blockIdx.x & 511;  // row-block
    const int rg   = rb * BM + r;

    const float* adj_base = adj + (size_t)rg * N + hf * 4096 + s * 8;
    const float* s2_base  = s2 + hf * 4096 + s * 8;
    const unsigned short* hb_base = hpk + ((size_t)hf * NSH << 13) + (wv << 11) + (lane << 3);
    float s1r = s1[rg];
    float eref = s1r + s2[rg];                    // diagonal logit (adj[i][i]=1)
    eref = eref > 0.f ? eref : ALPHA * eref;      // leaky_relu
    float lsum = 0.f;
    f32x4 acc = {0.f, 0.f, 0.f, 0.f};

    auto stage = [&](const ASP& p, int b) {
        const float* av0 = (const float*)&p.a0;
        const float* av1 = (const float*)&p.a1;
        const float* sv0 = (const float*)&p.s0;
        const float* sv1 = (const float*)&p.s1;
        float w[8];
#pragma unroll
        for (int z = 0; z < 4; ++z) {
            float e0 = s1r + sv0[z]; e0 = e0 > 0.f ? e0 : ALPHA * e0;   // leaky_relu
            float e1 = s1r + sv1[z]; e1 = e1 > 0.f ? e1 : ALPHA * e1;
            float w0 = __expf(e0 - eref);
            float w1 = __expf(e1 - eref);
            w[z]     = av0[z] > 0.f ? w0 : 0.f;
            w[z + 4] = av1[z] > 0.f ? w1 : 0.f;
        }
#pragma unroll
        for (int z = 0; z < 8; ++z) lsum += w[z];
        uint4 pk;
        pk.x = pk_bf16(w[0], w[1]); pk.y = pk_bf16(w[2], w[3]);
        pk.z = pk_bf16(w[4], w[5]); pk.w = pk_bf16(w[6], w[7]);
        *(uint4*)(&Pl[b][r * 256 + ((s * 16) ^ ((r & 7) << 4))]) = pk;
    };

    auto mfma_step = [&](int c, const UBP& u) {
        const unsigned char* Pc = Pl[c];
        const int i  = lane & 15;
        const int kb = lane >> 4;
        const uint4 ub[4] = {u.b0, u.b1, u.b2, u.b3};
#pragma unroll
        for (int kk = 0; kk < 4; ++kk) {
            uint4 ua = *(const uint4*)(Pc + i * 256 + ((kk * 64 + kb * 16) ^ ((i & 7) << 4)));
            acc = __builtin_amdgcn_mfma_f32_16x16x32_bf16(
                __builtin_bit_cast(bf16x8, ua), __builtin_bit_cast(bf16x8, ub[kk]),
                acc, 0, 0, 0);
        }
    };

    ASP AS_A, AS_B;            // even / odd step adj+s2
    UBP U_A, U_B;              // even / odd step B-frags
    issue_as(AS_A, adj_base, s2_base, 0);
    issue_as(AS_B, adj_base, s2_base, BK);
    issue_ub(U_A, hb_base, 0);
    issue_ub(U_B, hb_base, 1);
    stage(AS_A, 0);                              // step 0 -> buf0
    issue_as(AS_A, adj_base, s2_base, 2 * BK);   // step 2
    BARRIER();

    for (int p = 0; p < NSH; p += 2) {
        // even phase: compute step p (buf0), stage p+1 -> buf1
        mfma_step(0, U_A);
        if (p + 2 < NSH) issue_ub(U_A, hb_base, p + 2);
        stage(AS_B, 1);
        if (p + 3 < NSH) issue_as(AS_B, adj_base, s2_base, (p + 3) * BK);
        BARRIER();
        // odd phase: compute step p+1 (buf1), stage p+2 -> buf0
        mfma_step(1, U_B);
        if (p + 3 < NSH) issue_ub(U_B, hb_base, p + 3);
        if (p + 2 < NSH) {
            stage(AS_A, 0);
            if (p + 4 < NSH) issue_as(AS_A, adj_base, s2_base, (p + 4) * BK);
        }
        BARRIER();
    }

    // lsum: reduce over the 16 threads sharing row r; write partial
#pragma unroll
    for (int off = 8; off; off >>= 1) lsum += __shfl_xor(lsum, off, 64);
    if ((tid & 15) == 0) plsum[hf * N + rg] = lsum;

    // un-normalized partial numerators: C/D frag row i=(lane>>4)*4+reg, col lane&15
    const int dd = wv * 16 + (lane & 15);
#pragma unroll
    for (int reg = 0; reg < 4; ++reg) {
        int i = (lane >> 4) * 4 + reg;
        pacc[((size_t)hf * N + rb * BM + i) * 64 + dd] = acc[reg];
    }
}

// Kernel 3: combine the two K-halves, normalize, elu.
__global__ __launch_bounds__(256) void gat_reduce_kernel(
    const float* __restrict__ pacc, const float* __restrict__ plsum,
    float* __restrict__ out)
{
    int idx = blockIdx.x * 256 + threadIdx.x;    // over N*64
    int row = idx >> 6;
    float aa = pacc[idx] + pacc[(size_t)N * 64 + idx];
    float l  = plsum[row] + plsum[N + row];
    float o  = aa / l;
    out[idx] = o > 0.f ? o : expm1f(o);          // elu
}

extern "C" void kernel_launch(void* const* d_in, const int* in_sizes, int n_in,
                              void* d_out, int out_size, void* d_ws, size_t ws_size,
                              hipStream_t stream) {
    const float* input = (const float*)d_in[0];   // (8192, 512) f32
    const float* adj   = (const float*)d_in[1];   // (8192, 8192) f32
    const float* W     = (const float*)d_in[2];   // (512, 64) f32
    const float* a     = (const float*)d_in[3];   // (128, 1) f32
    float* out = (float*)d_out;                   // (8192, 64) f32

    unsigned short* hpk = (unsigned short*)d_ws;          // 1 MB fragment buffer
    float* s1    = (float*)(hpk + (size_t)N * D_OUT);     // N f32
    float* s2    = s1 + N;                                // N f32
    float* pacc  = s2 + N;                                // 2*N*64 f32 = 4 MB
    float* plsum = pacc + (size_t)2 * N * 64;             // 2*N f32

    gat_h_kernel<<<512, 256, 0, stream>>>(input, W, a, hpk, s1, s2);
    gat_flash_kernel<<<1024, 256, 0, stream>>>(adj, hpk, s1, s2, pacc, plsum);
    gat_reduce_kernel<<<N * 64 / 256, 256, 0, stream>>>(pacc, plsum, out);
}